// Round 1
// baseline (235.412 us; speedup 1.0000x reference)
//
#include <hip/hip_runtime.h>
#include <hip/hip_bf16.h>
#include <cmath>

// Problem constants (from reference)
#define N_TOK 16384   // 4*4096
#define DM    1024
#define NTILE 64
#define NCLUS 8
#define TPC   8
#define CH    256     // compress hidden
#define SGRID 16      // spline hidden

typedef __attribute__((ext_vector_type(8))) short short8;
typedef __attribute__((ext_vector_type(4))) float floatx4;

__device__ __forceinline__ unsigned short f2bf(float f) {
  union { float f; unsigned int u; } v; v.f = f;
  unsigned int r = v.u + 0x7FFFu + ((v.u >> 16) & 1u);  // RNE
  return (unsigned short)(r >> 16);
}

// ScoreCalibrationSpline: sigmoid -> lerp over knots (read knots from global, L1-hot)
__device__ __forceinline__ float calibrate(float s, const float* __restrict__ kn, float temp_eff) {
  float nrm = 1.0f / (1.0f + expf(-s / temp_eff));
  float idxf = nrm * 7.0f;
  int il = (int)idxf; if (il > 6) il = 6;   // nrm>0 so il>=0
  float tt = idxf - (float)il;
  float lo = kn[il], hi = kn[il + 1];
  return lo + tt * (hi - lo);
}

// ---------------- K0: prep ----------------
// blocks 0..3   : ternary q -> int8 [64][1024]; cluster sigs -> int8 [8][1024]
// blocks 4..131 : W1 fp32 [1024][256] -> bf16 pre-swizzled MFMA-B-frag layout:
//                 w1bf[kt*8192 + n*32 + g*8 + j] = bf16(W1[kt*32+g*8+j][n])
__global__ __launch_bounds__(256) void prep_kernel(
    const float* __restrict__ sig_raw, const float* __restrict__ w1,
    signed char* __restrict__ q8, signed char* __restrict__ c8,
    unsigned short* __restrict__ w1bf) {
  int bid = blockIdx.x, tid = threadIdx.x;
  if (bid < 4) {
    int d = bid * 256 + tid;
    for (int c = 0; c < 8; ++c) {
      float s = 0.f;
      for (int j = 0; j < 8; ++j) {
        int t = c * 8 + j;
        float r = sig_raw[t * DM + d];
        float qv = (r > 0.3f) ? 1.f : ((r < -0.3f) ? -1.f : 0.f);
        q8[t * DM + d] = (signed char)(int)qv;
        s += qv;
      }
      c8[c * DM + d] = (signed char)((s > 0.f) ? 1 : ((s < 0.f) ? -1 : 0));
    }
  } else {
    int g0 = (bid - 4) * 256 + tid;   // 0..32767 == (kt, n, g)
    int kt = g0 >> 10;
    int rem = g0 & 1023;
    int n = rem >> 2, g = rem & 3;
    int kbase = kt * 32 + g * 8;
    short8 v;
#pragma unroll
    for (int j = 0; j < 8; ++j) v[j] = (short)f2bf(w1[(kbase + j) * CH + n]);
    *(short8*)(w1bf + kt * 8192 + n * 32 + g * 8) = v;
  }
}

// ---------------- K1: compress GEMM (bf16 MFMA) + gelu + @W2 + tanh -> comp[N,2] ----------------
// Block: 16 rows x 256 cols, 4 waves each own 64 cols (4 n-tiles, 16 acc VGPRs).
__global__ __launch_bounds__(256) void gemm_comp_kernel(
    const float* __restrict__ x, const unsigned short* __restrict__ w1bf,
    const float* __restrict__ b1, const float* __restrict__ w2,
    const float* __restrict__ b2, float* __restrict__ comp_out) {
  __shared__ unsigned short Ash[16 * 32];   // 1 KB  (A tile, frag-friendly row-major)
  __shared__ unsigned short Bsh[8192];      // 16 KB (B k-tile, pre-swizzled frag layout)
  __shared__ float Psh[4][16][2];           // cross-wave comp partials

  int tid = threadIdx.x;
  int wave = tid >> 6, lane = tid & 63;
  int quad = lane >> 4, l15 = lane & 15;
  int m0 = blockIdx.x * 16;

  floatx4 acc[4];
#pragma unroll
  for (int i = 0; i < 4; ++i) acc[i] = (floatx4){0.f, 0.f, 0.f, 0.f};

  for (int kt = 0; kt < 32; ++kt) {
    __syncthreads();
    // stage A: 16 rows x 32 k fp32 -> bf16 (threads 0..63, 8 elems each)
    if (tid < 64) {
      int row = tid >> 2, kk = (tid & 3) * 8;
      const float* src = x + (size_t)(m0 + row) * DM + kt * 32 + kk;
      float4 a = *(const float4*)src;
      float4 b = *(const float4*)(src + 4);
      short8 v;
      v[0] = (short)f2bf(a.x); v[1] = (short)f2bf(a.y);
      v[2] = (short)f2bf(a.z); v[3] = (short)f2bf(a.w);
      v[4] = (short)f2bf(b.x); v[5] = (short)f2bf(b.y);
      v[6] = (short)f2bf(b.z); v[7] = (short)f2bf(b.w);
      *(short8*)(Ash + row * 32 + kk) = v;
    }
    // stage B: straight 16 KB copy (pre-swizzled in ws), 16B/lane
    {
      const uint4* bsrc = (const uint4*)(w1bf + kt * 8192);
      uint4* bdst = (uint4*)Bsh;
#pragma unroll
      for (int i = 0; i < 4; ++i) bdst[tid + 256 * i] = bsrc[tid + 256 * i];
    }
    __syncthreads();
    // A-frag: A[m=l15][k=quad*8+j] ; B-frag: B[k=quad*8+j][n=l15] (dense b128 reads)
    short8 a_frag = *(const short8*)(Ash + l15 * 32 + quad * 8);
#pragma unroll
    for (int nt = 0; nt < 4; ++nt) {
      int n = wave * 64 + nt * 16 + l15;
      short8 b_frag = *(const short8*)(Bsh + n * 32 + quad * 8);
      acc[nt] = __builtin_amdgcn_mfma_f32_16x16x32_bf16(a_frag, b_frag, acc[nt], 0, 0, 0);
    }
  }

  // epilogue: h = gelu(acc + b1); partial comp = h @ W2 over this lane's 4 cols
  float p0[4] = {0.f, 0.f, 0.f, 0.f}, p1[4] = {0.f, 0.f, 0.f, 0.f};
#pragma unroll
  for (int nt = 0; nt < 4; ++nt) {
    int col = wave * 64 + nt * 16 + l15;
    float b1c = b1[col], w20 = w2[col * 2], w21 = w2[col * 2 + 1];
#pragma unroll
    for (int r = 0; r < 4; ++r) {
      float h = acc[nt][r] + b1c;
      h = 0.5f * h * (1.0f + erff(h * 0.7071067811865475f));  // exact gelu
      p0[r] += h * w20;
      p1[r] += h * w21;
    }
  }
  // reduce across the 16 lanes of each quad (rows = quad*4 + r)
#pragma unroll
  for (int m = 1; m < 16; m <<= 1) {
#pragma unroll
    for (int r = 0; r < 4; ++r) {
      p0[r] += __shfl_xor(p0[r], m);
      p1[r] += __shfl_xor(p1[r], m);
    }
  }
  if (l15 == 0) {
#pragma unroll
    for (int r = 0; r < 4; ++r) {
      Psh[wave][quad * 4 + r][0] = p0[r];
      Psh[wave][quad * 4 + r][1] = p1[r];
    }
  }
  __syncthreads();
  if (tid < 16) {
    float s0 = b2[0], s1 = b2[1];
#pragma unroll
    for (int w = 0; w < 4; ++w) { s0 += Psh[w][tid][0]; s1 += Psh[w][tid][1]; }
    comp_out[(m0 + tid) * 2 + 0] = tanhf(s0);
    comp_out[(m0 + tid) * 2 + 1] = tanhf(s1);
  }
}

// ---------------- K2: routing + spline + residual + LayerNorm ----------------
// One wave per token. x row lives in registers, reused for routing dots and residual.
__global__ __launch_bounds__(256) void finalize_kernel(
    const float* __restrict__ x, const signed char* __restrict__ q8,
    const signed char* __restrict__ c8, const float* __restrict__ knots,
    const float* __restrict__ temperature, const float* __restrict__ comp_ws,
    const float* __restrict__ sw1, const float* __restrict__ sb1,
    const float* __restrict__ sw2, const float* __restrict__ sb2,
    const float* __restrict__ dirs, const float* __restrict__ gma,
    const float* __restrict__ bta, const float* __restrict__ oscale,
    float* __restrict__ out) {
  int tid = threadIdx.x;
  int wave = tid >> 6, lane = tid & 63;
  int tok = blockIdx.x * 4 + wave;
  const float* xr = x + (size_t)tok * DM;
  float4 xv[4];
#pragma unroll
  for (int i = 0; i < 4; ++i) xv[i] = *(const float4*)(xr + 4 * lane + 256 * i);
  float temp_eff = temperature[0] + 1e-6f;

  // cluster argmax over calibrated gates (calibrate is monotone; computed faithfully)
  int cid = 0; float bestg = -1e30f;
  for (int c = 0; c < 8; ++c) {
    const int* sp = (const int*)(c8 + (size_t)c * DM);
    float s = 0.f;
#pragma unroll
    for (int i = 0; i < 4; ++i) {
      int wv = sp[lane + 64 * i];
      float4 xi = xv[i];
      s += xi.x * (float)(signed char)(wv & 0xff);
      s += xi.y * (float)(signed char)((wv >> 8) & 0xff);
      s += xi.z * (float)(signed char)((wv >> 16) & 0xff);
      s += xi.w * (float)(wv >> 24);
    }
#pragma unroll
    for (int m = 1; m < 64; m <<= 1) s += __shfl_xor(s, m);
    float g = calibrate(s, knots, temp_eff);
    if (g > bestg) { bestg = g; cid = c; }
  }
  // within-cluster tile argmax
  int lidx = 0; bestg = -1e30f;
  for (int j = 0; j < 8; ++j) {
    const int* sp = (const int*)(q8 + (size_t)(cid * 8 + j) * DM);
    float s = 0.f;
#pragma unroll
    for (int i = 0; i < 4; ++i) {
      int wv = sp[lane + 64 * i];
      float4 xi = xv[i];
      s += xi.x * (float)(signed char)(wv & 0xff);
      s += xi.y * (float)(signed char)((wv >> 8) & 0xff);
      s += xi.z * (float)(signed char)((wv >> 16) & 0xff);
      s += xi.w * (float)(wv >> 24);
    }
#pragma unroll
    for (int m = 1; m < 64; m <<= 1) s += __shfl_xor(s, m);
    float g = calibrate(s, knots, temp_eff);
    if (g > bestg) { bestg = g; lidx = j; }
  }
  int t = cid * 8 + lidx;

  // tiny spline MLP (all lanes redundantly; loads are uniform -> L1 broadcast)
  float c0 = comp_ws[tok * 2], c1 = comp_ws[tok * 2 + 1];
  float mag = sb2[t];
#pragma unroll
  for (int g2 = 0; g2 < SGRID; ++g2) {
    float hh = c0 * sw1[t * 32 + g2] + c1 * sw1[t * 32 + 16 + g2] + sb1[t * 16 + g2];
    hh = fmaxf(hh, 0.f);
    mag += hh * sw2[t * 16 + g2];
  }
  float scale = mag * oscale[0];

  // residual + LayerNorm (two-pass in registers)
  const float* dr = dirs + (size_t)t * DM;
  float4 fv[4];
  float ssum = 0.f;
#pragma unroll
  for (int i = 0; i < 4; ++i) {
    float4 d4 = *(const float4*)(dr + 4 * lane + 256 * i);
    fv[i].x = xv[i].x + scale * d4.x;
    fv[i].y = xv[i].y + scale * d4.y;
    fv[i].z = xv[i].z + scale * d4.z;
    fv[i].w = xv[i].w + scale * d4.w;
    ssum += fv[i].x + fv[i].y + fv[i].z + fv[i].w;
  }
#pragma unroll
  for (int m = 1; m < 64; m <<= 1) ssum += __shfl_xor(ssum, m);
  float mu = ssum * (1.0f / 1024.0f);
  float vs = 0.f;
#pragma unroll
  for (int i = 0; i < 4; ++i) {
    float d0 = fv[i].x - mu, d1 = fv[i].y - mu, d2 = fv[i].z - mu, d3 = fv[i].w - mu;
    vs += d0 * d0 + d1 * d1 + d2 * d2 + d3 * d3;
  }
#pragma unroll
  for (int m = 1; m < 64; m <<= 1) vs += __shfl_xor(vs, m);
  float inv = rsqrtf(vs * (1.0f / 1024.0f) + 1e-5f);

  float* orow = out + (size_t)tok * DM;
#pragma unroll
  for (int i = 0; i < 4; ++i) {
    float4 g4 = *(const float4*)(gma + 4 * lane + 256 * i);
    float4 b4 = *(const float4*)(bta + 4 * lane + 256 * i);
    float4 o;
    o.x = (fv[i].x - mu) * inv * g4.x + b4.x;
    o.y = (fv[i].y - mu) * inv * g4.y + b4.y;
    o.z = (fv[i].z - mu) * inv * g4.z + b4.z;
    o.w = (fv[i].w - mu) * inv * g4.w + b4.w;
    *(float4*)(orow + 4 * lane + 256 * i) = o;
  }
}

extern "C" void kernel_launch(void* const* d_in, const int* in_sizes, int n_in,
                              void* d_out, int out_size, void* d_ws, size_t ws_size,
                              hipStream_t stream) {
  const float* x      = (const float*)d_in[0];
  const float* sigraw = (const float*)d_in[1];
  const float* knots  = (const float*)d_in[2];
  const float* temp   = (const float*)d_in[3];
  const float* cw1    = (const float*)d_in[4];
  const float* cb1    = (const float*)d_in[5];
  const float* cw2    = (const float*)d_in[6];
  const float* cb2    = (const float*)d_in[7];
  const float* sw1    = (const float*)d_in[8];
  const float* sb1    = (const float*)d_in[9];
  const float* sw2    = (const float*)d_in[10];
  const float* sb2    = (const float*)d_in[11];
  const float* dirs   = (const float*)d_in[12];
  const float* gma    = (const float*)d_in[13];
  const float* bta    = (const float*)d_in[14];
  const float* oscale = (const float*)d_in[15];
  float* out = (float*)d_out;

  // ws layout (total 729,088 B)
  char* ws = (char*)d_ws;
  signed char* q8       = (signed char*)ws;                  // 65536 B
  signed char* c8       = (signed char*)(ws + 65536);        // 8192 B
  unsigned short* w1bf  = (unsigned short*)(ws + 73728);     // 524288 B
  float* comp           = (float*)(ws + 598016);             // 131072 B

  hipLaunchKernelGGL(prep_kernel, dim3(132), dim3(256), 0, stream,
                     sigraw, cw1, q8, c8, w1bf);
  hipLaunchKernelGGL(gemm_comp_kernel, dim3(N_TOK / 16), dim3(256), 0, stream,
                     x, w1bf, cb1, cw2, cb2, comp);
  hipLaunchKernelGGL(finalize_kernel, dim3(N_TOK / 4), dim3(256), 0, stream,
                     x, q8, c8, knots, temp, comp,
                     sw1, sb1, sw2, sb2, dirs, gma, bta, oscale, out);
}

// Round 2
// 199.752 us; speedup vs baseline: 1.1785x; 1.1785x over previous
//
#include <hip/hip_runtime.h>
#include <hip/hip_bf16.h>
#include <cmath>

// Problem constants
#define N_TOK 16384   // 4*4096
#define DM    1024
#define CH    256     // compress hidden
#define SGRID 16
#define NB    352     // padded GEMM N: 256 W1 + 8 cluster + 64 tile + 24 pad
#define NSC   72      // scores per token (8 cluster + 64 tile)
// B chunk layout (per kt, BK=64): chunk c = nt*128 + ks*64 + quad*16 + l15 (16B each)
// chunk holds B[k = kt*64+ks*32+quad*8+j][n = nt*16+l15], j=0..7
#define CHUNKS_PER_KT 2816            // NB/16 * 8
#define KT_BYTES      45056           // CHUNKS_PER_KT*16
#define KT_USHORT     22528

typedef __attribute__((ext_vector_type(8))) short short8;
typedef __attribute__((ext_vector_type(4))) float floatx4;

__device__ __forceinline__ unsigned short f2bf(float f) {
  union { float f; unsigned int u; } v; v.f = f;
  unsigned int r = v.u + 0x7FFFu + ((v.u >> 16) & 1u);  // RNE
  return (unsigned short)(r >> 16);
}

__device__ __forceinline__ float calibrate(float s, const float* __restrict__ kn, float temp_eff) {
  float nrm = 1.0f / (1.0f + expf(-s / temp_eff));
  float idxf = nrm * 7.0f;
  int il = (int)idxf; if (il > 6) il = 6;
  float tt = idxf - (float)il;
  float lo = kn[il], hi = kn[il + 1];
  return lo + tt * (hi - lo);
}

// ---------------- K0: prep extended pre-swizzled B (bf16) ----------------
// blocks 0..63  : W1 [1024][256] -> cols 0..255   (LDS-tiled transpose)
// blocks 64..111: sig cols 256..351 (cluster sign / ternary tile / zero pad)
__global__ __launch_bounds__(256) void prep_kernel(
    const float* __restrict__ sig_raw, const float* __restrict__ w1,
    unsigned short* __restrict__ wsB) {
  int bid = blockIdx.x, tid = threadIdx.x;
  if (bid < 64) {
    __shared__ float tile[64 * 68];
    int ng = bid & 3, kt = bid >> 2;
    int r = tid >> 2, cb = (tid & 3) * 16;
    const float* src = w1 + (size_t)(kt * 64 + r) * CH + ng * 64 + cb;
#pragma unroll
    for (int i = 0; i < 4; ++i)
      *(float4*)(tile + r * 68 + cb + 4 * i) = *(const float4*)(src + 4 * i);
    __syncthreads();
#pragma unroll
    for (int h = 0; h < 2; ++h) {
      int cl = h * 256 + tid;                 // 0..511 local chunk
      int ntl = cl >> 7, rest = cl & 127;
      int ks = rest >> 6, quad = (rest >> 4) & 3, l15 = rest & 15;
      int nl = ntl * 16 + l15;                // local col 0..63
      int kl = ks * 32 + quad * 8;            // local k base 0..56
      short8 v;
#pragma unroll
      for (int j = 0; j < 8; ++j) v[j] = (short)f2bf(tile[(kl + j) * 68 + nl]);
      int c = (ng * 4 + ntl) * 128 + rest;
      *(short8*)(wsB + (size_t)kt * KT_USHORT + c * 8) = v;
    }
  } else {
    int g = (bid - 64) * 256 + tid;           // 0..12287
    int kt = g / 768, rem = g % 768;
    int ntl = rem >> 7, rest = rem & 127;
    int nt = 16 + ntl;
    int ks = rest >> 6, quad = (rest >> 4) & 3, l15 = rest & 15;
    int n = nt * 16 + l15;                    // 256..351
    int k0 = kt * 64 + ks * 32 + quad * 8;
    short8 v;
#pragma unroll
    for (int j = 0; j < 8; ++j) {
      int k = k0 + j;
      unsigned short bv = 0;
      if (n < 264) {                          // cluster signature col
        int cl2 = n - 256;
        float s = 0.f;
#pragma unroll
        for (int m = 0; m < 8; ++m) {
          float rr = sig_raw[(size_t)(cl2 * 8 + m) * DM + k];
          s += (rr > 0.3f) ? 1.f : ((rr < -0.3f) ? -1.f : 0.f);
        }
        bv = (s > 0.f) ? 0x3F80u : ((s < 0.f) ? 0xBF80u : 0u);
      } else if (n < 328) {                   // ternary tile signature col
        float rr = sig_raw[(size_t)(n - 264) * DM + k];
        bv = (rr > 0.3f) ? 0x3F80u : ((rr < -0.3f) ? 0xBF80u : 0u);
      }
      v[j] = (short)bv;
    }
    *(short8*)(wsB + (size_t)kt * KT_USHORT + (nt * 128 + rest) * 8) = v;
  }
}

// ---------------- K1: fused GEMM (comp + routing scores) ----------------
// Block: 64 rows x 352 cols. 4 waves; wave w owns n-tiles {t : t%4==w, t<21}.
__global__ __launch_bounds__(256, 2) void gemm_kernel(
    const float* __restrict__ x, const unsigned short* __restrict__ wsB,
    const float* __restrict__ b1, const float* __restrict__ w2,
    const float* __restrict__ b2, float* __restrict__ comp_out,
    float* __restrict__ score_ws) {
  __shared__ unsigned short Ash[64 * 72];     // 9216 B, row stride 144B (2-way only)
  __shared__ unsigned short Bsh[KT_USHORT];   // 45056 B, chunk order
  __shared__ float Psh[4][64][2];

  int tid = threadIdx.x;
  int wave = tid >> 6, lane = tid & 63, quad = lane >> 4, l15 = lane & 15;
  int m0 = blockIdx.x * 64;

  floatx4 acc[6][4];
#pragma unroll
  for (int s = 0; s < 6; ++s)
#pragma unroll
    for (int mt = 0; mt < 4; ++mt) acc[s][mt] = (floatx4){0.f, 0.f, 0.f, 0.f};

  int arow = tid >> 2, akk = (tid & 3) * 16;
  const float* asrc = x + (size_t)(m0 + arow) * DM + akk;

  for (int kt = 0; kt < 16; ++kt) {
    __syncthreads();
    // B stage: pure 16B-per-lane DMA, contiguous in both global and LDS
    {
      const char* gB = (const char*)wsB + (size_t)kt * KT_BYTES;
      char* lB = (char*)Bsh;
#pragma unroll
      for (int i = 0; i < 11; ++i) {
        int off = (i * 4 + wave) * 1024;      // 64 chunks * 16B
        __builtin_amdgcn_global_load_lds(
            (const __attribute__((address_space(1))) void*)(gB + off + lane * 16),
            (__attribute__((address_space(3))) void*)(lB + off), 16, 0, 0);
      }
    }
    // A stage: 64 rows x 64 k, fp32 -> bf16
    {
      const float* s = asrc + kt * 64;
      float4 f0 = ((const float4*)s)[0], f1 = ((const float4*)s)[1];
      float4 f2 = ((const float4*)s)[2], f3 = ((const float4*)s)[3];
      short8 v0, v1;
      v0[0] = (short)f2bf(f0.x); v0[1] = (short)f2bf(f0.y);
      v0[2] = (short)f2bf(f0.z); v0[3] = (short)f2bf(f0.w);
      v0[4] = (short)f2bf(f1.x); v0[5] = (short)f2bf(f1.y);
      v0[6] = (short)f2bf(f1.z); v0[7] = (short)f2bf(f1.w);
      v1[0] = (short)f2bf(f2.x); v1[1] = (short)f2bf(f2.y);
      v1[2] = (short)f2bf(f2.z); v1[3] = (short)f2bf(f2.w);
      v1[4] = (short)f2bf(f3.x); v1[5] = (short)f2bf(f3.y);
      v1[6] = (short)f2bf(f3.z); v1[7] = (short)f2bf(f3.w);
      *(short8*)(Ash + arow * 72 + akk) = v0;
      *(short8*)(Ash + arow * 72 + akk + 8) = v1;
    }
    __syncthreads();
#pragma unroll
    for (int ks = 0; ks < 2; ++ks) {
      short8 a[4];
#pragma unroll
      for (int mt = 0; mt < 4; ++mt)
        a[mt] = *(const short8*)(Ash + (mt * 16 + l15) * 72 + ks * 32 + quad * 8);
#pragma unroll
      for (int s = 0; s < 5; ++s) {
        int nt = wave + s * 4;
        short8 b = *(const short8*)(Bsh + (nt * 128 + ks * 64 + quad * 16 + l15) * 8);
#pragma unroll
        for (int mt = 0; mt < 4; ++mt)
          acc[s][mt] = __builtin_amdgcn_mfma_f32_16x16x32_bf16(a[mt], b, acc[s][mt], 0, 0, 0);
      }
      if (wave == 0) {                        // extra tile 20
        short8 b = *(const short8*)(Bsh + (20 * 128 + ks * 64 + quad * 16 + l15) * 8);
#pragma unroll
        for (int mt = 0; mt < 4; ++mt)
          acc[5][mt] = __builtin_amdgcn_mfma_f32_16x16x32_bf16(a[mt], b, acc[5][mt], 0, 0, 0);
      }
    }
  }

  // ---- epilogue 1: comp = tanh(gelu(h+b1)@W2 + b2) over W1 tiles (s=0..3) ----
  float p0[4][4], p1[4][4];
#pragma unroll
  for (int mt = 0; mt < 4; ++mt)
#pragma unroll
    for (int r = 0; r < 4; ++r) { p0[mt][r] = 0.f; p1[mt][r] = 0.f; }
#pragma unroll
  for (int s = 0; s < 4; ++s) {
    int col = (wave + s * 4) * 16 + l15;      // < 256
    float b1c = b1[col], w20 = w2[2 * col], w21 = w2[2 * col + 1];
#pragma unroll
    for (int mt = 0; mt < 4; ++mt)
#pragma unroll
      for (int r = 0; r < 4; ++r) {
        float h = acc[s][mt][r] + b1c;
        h = 0.5f * h * (1.0f + erff(h * 0.7071067811865475f));
        p0[mt][r] += h * w20;
        p1[mt][r] += h * w21;
      }
  }
#pragma unroll
  for (int m = 1; m < 16; m <<= 1)
#pragma unroll
    for (int mt = 0; mt < 4; ++mt)
#pragma unroll
      for (int r = 0; r < 4; ++r) {
        p0[mt][r] += __shfl_xor(p0[mt][r], m);
        p1[mt][r] += __shfl_xor(p1[mt][r], m);
      }
  if (l15 == 0) {
#pragma unroll
    for (int mt = 0; mt < 4; ++mt)
#pragma unroll
      for (int r = 0; r < 4; ++r) {
        Psh[wave][mt * 16 + quad * 4 + r][0] = p0[mt][r];
        Psh[wave][mt * 16 + quad * 4 + r][1] = p1[mt][r];
      }
  }
  // ---- epilogue 2: raw routing scores -> ws ----
  {
    int cs = wave * 16 + l15;                 // tile nt=wave+16 -> score col 0..63
#pragma unroll
    for (int mt = 0; mt < 4; ++mt)
#pragma unroll
      for (int r = 0; r < 4; ++r)
        score_ws[(size_t)(m0 + mt * 16 + quad * 4 + r) * NSC + cs] = acc[4][mt][r];
    if (wave == 0 && l15 < 8) {               // tile 20 -> score cols 64..71
#pragma unroll
      for (int mt = 0; mt < 4; ++mt)
#pragma unroll
        for (int r = 0; r < 4; ++r)
          score_ws[(size_t)(m0 + mt * 16 + quad * 4 + r) * NSC + 64 + l15] = acc[5][mt][r];
    }
  }
  __syncthreads();
  if (tid < 64) {
    float s0 = b2[0], s1 = b2[1];
#pragma unroll
    for (int w = 0; w < 4; ++w) { s0 += Psh[w][tid][0]; s1 += Psh[w][tid][1]; }
    comp_out[(m0 + tid) * 2 + 0] = tanhf(s0);
    comp_out[(m0 + tid) * 2 + 1] = tanhf(s1);
  }
}

// ---------------- K2: calibrate+argmax + spline + residual + LayerNorm ----------------
__global__ __launch_bounds__(256) void finalize_kernel(
    const float* __restrict__ x, const float* __restrict__ score_ws,
    const float* __restrict__ knots, const float* __restrict__ temperature,
    const float* __restrict__ comp_ws, const float* __restrict__ sw1,
    const float* __restrict__ sb1, const float* __restrict__ sw2,
    const float* __restrict__ sb2, const float* __restrict__ dirs,
    const float* __restrict__ gma, const float* __restrict__ bta,
    const float* __restrict__ oscale, float* __restrict__ out) {
  int tid = threadIdx.x;
  int wave = tid >> 6, lane = tid & 63;
  int tok = blockIdx.x * 4 + wave;
  const float* xr = x + (size_t)tok * DM;
  float4 xv[4];
#pragma unroll
  for (int i = 0; i < 4; ++i) xv[i] = *(const float4*)(xr + 4 * lane + 256 * i);

  float temp_eff = temperature[0] + 1e-6f;
  const float* sc = score_ws + (size_t)tok * NSC;

  // cluster argmax (calibrate monotone but faithful for tie-break semantics)
  int cid = 0; float best = -1e30f;
#pragma unroll
  for (int c = 0; c < 8; ++c) {
    float g = calibrate(sc[c], knots, temp_eff);
    if (g > best) { best = g; cid = c; }
  }
  int lidx = 0; best = -1e30f;
#pragma unroll
  for (int j = 0; j < 8; ++j) {
    float g = calibrate(sc[8 + cid * 8 + j], knots, temp_eff);
    if (g > best) { best = g; lidx = j; }
  }
  int t = cid * 8 + lidx;

  // tiny spline MLP (uniform within wave)
  float c0 = comp_ws[tok * 2], c1 = comp_ws[tok * 2 + 1];
  float mag = sb2[t];
#pragma unroll
  for (int g2 = 0; g2 < SGRID; ++g2) {
    float hh = c0 * sw1[t * 32 + g2] + c1 * sw1[t * 32 + 16 + g2] + sb1[t * 16 + g2];
    hh = fmaxf(hh, 0.f);
    mag += hh * sw2[t * 16 + g2];
  }
  float scale = mag * oscale[0];

  // residual + LayerNorm
  const float* dr = dirs + (size_t)t * DM;
  float4 fv[4];
  float ssum = 0.f;
#pragma unroll
  for (int i = 0; i < 4; ++i) {
    float4 d4 = *(const float4*)(dr + 4 * lane + 256 * i);
    fv[i].x = xv[i].x + scale * d4.x;
    fv[i].y = xv[i].y + scale * d4.y;
    fv[i].z = xv[i].z + scale * d4.z;
    fv[i].w = xv[i].w + scale * d4.w;
    ssum += fv[i].x + fv[i].y + fv[i].z + fv[i].w;
  }
#pragma unroll
  for (int m = 1; m < 64; m <<= 1) ssum += __shfl_xor(ssum, m);
  float mu = ssum * (1.0f / 1024.0f);
  float vs = 0.f;
#pragma unroll
  for (int i = 0; i < 4; ++i) {
    float d0 = fv[i].x - mu, d1 = fv[i].y - mu, d2 = fv[i].z - mu, d3 = fv[i].w - mu;
    vs += d0 * d0 + d1 * d1 + d2 * d2 + d3 * d3;
  }
#pragma unroll
  for (int m = 1; m < 64; m <<= 1) vs += __shfl_xor(vs, m);
  float inv = rsqrtf(vs * (1.0f / 1024.0f) + 1e-5f);

  float* orow = out + (size_t)tok * DM;
#pragma unroll
  for (int i = 0; i < 4; ++i) {
    float4 g4 = *(const float4*)(gma + 4 * lane + 256 * i);
    float4 b4 = *(const float4*)(bta + 4 * lane + 256 * i);
    float4 o;
    o.x = (fv[i].x - mu) * inv * g4.x + b4.x;
    o.y = (fv[i].y - mu) * inv * g4.y + b4.y;
    o.z = (fv[i].z - mu) * inv * g4.z + b4.z;
    o.w = (fv[i].w - mu) * inv * g4.w + b4.w;
    *(float4*)(orow + 4 * lane + 256 * i) = o;
  }
}

extern "C" void kernel_launch(void* const* d_in, const int* in_sizes, int n_in,
                              void* d_out, int out_size, void* d_ws, size_t ws_size,
                              hipStream_t stream) {
  const float* x      = (const float*)d_in[0];
  const float* sigraw = (const float*)d_in[1];
  const float* knots  = (const float*)d_in[2];
  const float* temp   = (const float*)d_in[3];
  const float* cw1    = (const float*)d_in[4];
  const float* cb1    = (const float*)d_in[5];
  const float* cw2    = (const float*)d_in[6];
  const float* cb2    = (const float*)d_in[7];
  const float* sw1    = (const float*)d_in[8];
  const float* sb1    = (const float*)d_in[9];
  const float* sw2    = (const float*)d_in[10];
  const float* sb2    = (const float*)d_in[11];
  const float* dirs   = (const float*)d_in[12];
  const float* gma    = (const float*)d_in[13];
  const float* bta    = (const float*)d_in[14];
  const float* oscale = (const float*)d_in[15];
  float* out = (float*)d_out;

  // ws layout: wsB 720896 B | score_ws 4718592 B | comp 131072 B  (~5.6 MB)
  char* ws = (char*)d_ws;
  unsigned short* wsB = (unsigned short*)ws;
  float* score_ws     = (float*)(ws + 720896);
  float* comp         = (float*)(ws + 720896 + 4718592);

  hipLaunchKernelGGL(prep_kernel, dim3(112), dim3(256), 0, stream,
                     sigraw, cw1, wsB);
  hipLaunchKernelGGL(gemm_kernel, dim3(N_TOK / 64), dim3(256), 0, stream,
                     x, wsB, cb1, cw2, cb2, comp, score_ws);
  hipLaunchKernelGGL(finalize_kernel, dim3(N_TOK / 4), dim3(256), 0, stream,
                     x, score_ws, knots, temp, comp,
                     sw1, sb1, sw2, sb2, dirs, gma, bta, oscale, out);
}

// Round 3
// 198.413 us; speedup vs baseline: 1.1865x; 1.0068x over previous
//
#include <hip/hip_runtime.h>
#include <hip/hip_bf16.h>
#include <cmath>

// Problem constants
#define N_TOK 16384   // 4*4096
#define DM    1024
#define CH    256
#define SGRID 16
#define NTP   24      // padded n-tiles (21 real: 16 W1 + 4.5 score, 3 junk)
// wsB layout (ushort): [((kk*24 + nt)*64 + lane)*8 + j] = bf16(B[k][n])
//   k = kk*32 + (lane>>4)*8 + j, n = nt*16 + (lane&15), kk in [0,32)
// -> each (kk,nt) fragment is 1024 contiguous bytes, lane-ordered.

typedef __attribute__((ext_vector_type(8))) short short8;
typedef __attribute__((ext_vector_type(4))) float floatx4;

__device__ __forceinline__ unsigned short f2bf(float f) {
  union { float f; unsigned int u; } v; v.f = f;
  unsigned int r = v.u + 0x7FFFu + ((v.u >> 16) & 1u);  // RNE
  return (unsigned short)(r >> 16);
}

__device__ __forceinline__ short8 cvt8(float4 u, float4 v) {
  union { short8 s; __hip_bfloat162 h[4]; } r;
  r.h[0] = __float22bfloat162_rn(make_float2(u.x, u.y));
  r.h[1] = __float22bfloat162_rn(make_float2(u.z, u.w));
  r.h[2] = __float22bfloat162_rn(make_float2(v.x, v.y));
  r.h[3] = __float22bfloat162_rn(make_float2(v.z, v.w));
  return r.s;
}

__device__ __forceinline__ float calibrate(float s, const float* __restrict__ kn, float temp_eff) {
  float nrm = 1.0f / (1.0f + expf(-s / temp_eff));
  float idxf = nrm * 7.0f;
  int il = (int)idxf; if (il > 6) il = 6;
  float tt = idxf - (float)il;
  float lo = kn[il], hi = kn[il + 1];
  return lo + tt * (hi - lo);
}

// ---------------- K0: prep swizzled B (grid 32 = one block per kk) ----------------
__global__ __launch_bounds__(256) void prep_kernel(
    const float* __restrict__ sig_raw, const float* __restrict__ w1,
    unsigned short* __restrict__ wsB) {
  __shared__ float Wt[32][260];   // W1 rows kk*32..+31, all 256 cols
  __shared__ float St[64][33];    // ternarized sig, 64 tiles x 32 k
  int kk = blockIdx.x, tid = threadIdx.x;
  {
    int r = tid >> 3, c0 = (tid & 7) * 32;
    const float* src = w1 + (size_t)(kk * 32 + r) * CH + c0;
#pragma unroll
    for (int i = 0; i < 8; ++i)
      *(float4*)(&Wt[r][c0 + 4 * i]) = *(const float4*)(src + 4 * i);
  }
  {
    int t = tid >> 2, c0 = (tid & 3) * 8;
    const float* src = sig_raw + (size_t)t * DM + kk * 32 + c0;
#pragma unroll
    for (int i = 0; i < 8; ++i) {
      float rr = src[i];
      St[t][c0 + i] = (rr > 0.3f) ? 1.f : ((rr < -0.3f) ? -1.f : 0.f);
    }
  }
  __syncthreads();
  // W1 tiles nt=0..15
#pragma unroll
  for (int i = 0; i < 4; ++i) {
    int idx = i * 256 + tid;             // 0..1023 = (nt, lane)
    int nt = idx >> 6, lane = idx & 63;
    int q = lane >> 4, l = lane & 15;
    short8 v;
#pragma unroll
    for (int j = 0; j < 8; ++j) v[j] = (short)f2bf(Wt[q * 8 + j][nt * 16 + l]);
    *(short8*)(wsB + ((size_t)(kk * NTP + nt) * 64 + lane) * 8) = v;
  }
  // sig tiles nt=16..20
#pragma unroll
  for (int i = 0; i < 2; ++i) {
    int idx = i * 256 + tid;
    if (idx < 320) {
      int nt = 16 + (idx >> 6), lane = idx & 63;
      int q = lane >> 4, l = lane & 15;
      int n = nt * 16 + l;
      short8 v;
#pragma unroll
      for (int j = 0; j < 8; ++j) {
        int kl = q * 8 + j;
        float val = 0.f;
        if (n < 264) {
          float s = 0.f;
#pragma unroll
          for (int m = 0; m < 8; ++m) s += St[(n - 256) * 8 + m][kl];
          val = (s > 0.f) ? 1.f : ((s < 0.f) ? -1.f : 0.f);
        } else if (n < 328) {
          val = St[n - 264][kl];
        }
        v[j] = (short)f2bf(val);
      }
      *(short8*)(wsB + ((size_t)(kk * NTP + nt) * 64 + lane) * 8) = v;
    }
  }
}

// ---------------- K1: fused GEMM + routing + spline + residual + LN ----------------
// grid 256 (64 tokens/block), 512 threads (8 waves). No LDS / no barriers in K-loop.
// wave w: m-half h=w>>2 (m-tiles 2h,2h+1), n-tiles (w&3)+4s, s=0..5.
#define LOADK(kk, bv, av)                                                   \
  {                                                                         \
    const char* bp = bBase + (size_t)(kk) * (NTP * 1024);                   \
    _Pragma("unroll") for (int s = 0; s < 6; ++s)                           \
        bv[s] = *(const short8*)(bp + s * 4096);                            \
    const float* ap0 = aBase0 + (kk) * 32;                                  \
    av[0][0] = *(const float4*)(ap0);                                       \
    av[0][1] = *(const float4*)(ap0 + 4);                                   \
    const float* ap1 = aBase1 + (kk) * 32;                                  \
    av[1][0] = *(const float4*)(ap1);                                       \
    av[1][1] = *(const float4*)(ap1 + 4);                                   \
  }

#define COMPUTE(bv, av)                                                     \
  {                                                                         \
    short8 aa0 = cvt8(av[0][0], av[0][1]);                                  \
    short8 aa1 = cvt8(av[1][0], av[1][1]);                                  \
    _Pragma("unroll") for (int s = 0; s < 6; ++s) {                         \
      acc[s][0] = __builtin_amdgcn_mfma_f32_16x16x32_bf16(aa0, bv[s], acc[s][0], 0, 0, 0); \
      acc[s][1] = __builtin_amdgcn_mfma_f32_16x16x32_bf16(aa1, bv[s], acc[s][1], 0, 0, 0); \
    }                                                                       \
  }

__global__ __launch_bounds__(512, 2) void fused_kernel(
    const float* __restrict__ x, const unsigned short* __restrict__ wsB,
    const float* __restrict__ b1, const float* __restrict__ w2,
    const float* __restrict__ b2, const float* __restrict__ knots,
    const float* __restrict__ temperature, const float* __restrict__ sw1,
    const float* __restrict__ sb1, const float* __restrict__ sw2,
    const float* __restrict__ sb2, const float* __restrict__ dirs,
    const float* __restrict__ gma, const float* __restrict__ bta,
    const float* __restrict__ oscale, float* __restrict__ out) {
  __shared__ float Ssc[64][81];     // scores: [token][sc] sc0..7=cluster, 8..71=tile
  __shared__ float Psh[8][32][3];   // comp partials per wave
  __shared__ float ScaleS[64];
  __shared__ int   TidxS[64];

  int tid = threadIdx.x;
  int wave = tid >> 6, lane = tid & 63, quad = lane >> 4, l15 = lane & 15;
  int w3 = wave & 3, h = wave >> 2;
  int m0 = blockIdx.x * 64;

  floatx4 acc[6][2];
#pragma unroll
  for (int s = 0; s < 6; ++s) {
    acc[s][0] = (floatx4){0.f, 0.f, 0.f, 0.f};
    acc[s][1] = (floatx4){0.f, 0.f, 0.f, 0.f};
  }

  const char* bBase = (const char*)wsB + w3 * 1024 + lane * 16;
  const float* aBase0 = x + (size_t)(m0 + h * 32 + l15) * DM + quad * 8;
  const float* aBase1 = aBase0 + 16 * DM;

  short8 bA[6], bB_[6];
  float4 aA[2][2], aB_[2][2];
  LOADK(0, bA, aA);
#pragma unroll 1
  for (int kk = 0; kk < 30; kk += 2) {
    LOADK(kk + 1, bB_, aB_);
    COMPUTE(bA, aA);
    LOADK(kk + 2, bA, aA);
    COMPUTE(bB_, aB_);
  }
  LOADK(31, bB_, aB_);
  COMPUTE(bA, aA);
  COMPUTE(bB_, aB_);

  // ---- scores -> LDS (s=4 all waves; s=5 only w3==0 -> sc 64..79) ----
#pragma unroll
  for (int mt2 = 0; mt2 < 2; ++mt2)
#pragma unroll
    for (int r = 0; r < 4; ++r) {
      int row = h * 32 + mt2 * 16 + quad * 4 + r;
      Ssc[row][w3 * 16 + l15] = acc[4][mt2][r];
      if (w3 == 0) Ssc[row][64 + l15] = acc[5][mt2][r];
    }

  // ---- comp partials over W1 tiles (s=0..3) ----
  float p0[2][4], p1[2][4];
#pragma unroll
  for (int mt2 = 0; mt2 < 2; ++mt2)
#pragma unroll
    for (int r = 0; r < 4; ++r) { p0[mt2][r] = 0.f; p1[mt2][r] = 0.f; }
#pragma unroll
  for (int s = 0; s < 4; ++s) {
    int col = (w3 + 4 * s) * 16 + l15;
    float b1c = b1[col], w20 = w2[2 * col], w21 = w2[2 * col + 1];
#pragma unroll
    for (int mt2 = 0; mt2 < 2; ++mt2)
#pragma unroll
      for (int r = 0; r < 4; ++r) {
        float hh = acc[s][mt2][r] + b1c;
        hh = 0.5f * hh * (1.0f + erff(hh * 0.7071067811865475f));
        p0[mt2][r] += hh * w20;
        p1[mt2][r] += hh * w21;
      }
  }
#pragma unroll
  for (int m = 1; m < 16; m <<= 1)
#pragma unroll
    for (int mt2 = 0; mt2 < 2; ++mt2)
#pragma unroll
      for (int r = 0; r < 4; ++r) {
        p0[mt2][r] += __shfl_xor(p0[mt2][r], m);
        p1[mt2][r] += __shfl_xor(p1[mt2][r], m);
      }
  if (l15 == 0) {
#pragma unroll
    for (int mt2 = 0; mt2 < 2; ++mt2)
#pragma unroll
      for (int r = 0; r < 4; ++r) {
        Psh[wave][mt2 * 16 + quad * 4 + r][0] = p0[mt2][r];
        Psh[wave][mt2 * 16 + quad * 4 + r][1] = p1[mt2][r];
      }
  }
  __syncthreads();

  // ---- per-token: comp combine + routing + spline ----
  if (tid < 64) {
    int row = tid, hh2 = row >> 5, rl = row & 31;
    float s0 = b2[0], s1 = b2[1];
#pragma unroll
    for (int j = 0; j < 4; ++j) {
      s0 += Psh[hh2 * 4 + j][rl][0];
      s1 += Psh[hh2 * 4 + j][rl][1];
    }
    float c0 = tanhf(s0), c1 = tanhf(s1);

    float temp_eff = temperature[0] + 1e-6f;
    int cid = 0; float best = -1e30f;
#pragma unroll
    for (int c = 0; c < 8; ++c) {
      float g = calibrate(Ssc[row][c], knots, temp_eff);
      if (g > best) { best = g; cid = c; }
    }
    int lidx = 0; best = -1e30f;
#pragma unroll
    for (int j = 0; j < 8; ++j) {
      float g = calibrate(Ssc[row][8 + cid * 8 + j], knots, temp_eff);
      if (g > best) { best = g; lidx = j; }
    }
    int t = cid * 8 + lidx;

    float mag = sb2[t];
#pragma unroll
    for (int g2 = 0; g2 < SGRID; ++g2) {
      float hv = c0 * sw1[t * 32 + g2] + c1 * sw1[t * 32 + 16 + g2] + sb1[t * 16 + g2];
      hv = fmaxf(hv, 0.f);
      mag += hv * sw2[t * 16 + g2];
    }
    ScaleS[row] = mag * oscale[0];
    TidxS[row] = t;
  }
  __syncthreads();

  // ---- residual + LayerNorm: wave w -> rows w*8 .. w*8+7 ----
  float4 g4[4], be4[4];
#pragma unroll
  for (int i = 0; i < 4; ++i) {
    g4[i] = *(const float4*)(gma + 4 * lane + 256 * i);
    be4[i] = *(const float4*)(bta + 4 * lane + 256 * i);
  }
#pragma unroll 1
  for (int rr = 0; rr < 8; ++rr) {
    int row = wave * 8 + rr;
    float scale = ScaleS[row];
    const float* xr = x + (size_t)(m0 + row) * DM;
    const float* dr = dirs + (size_t)TidxS[row] * DM;
    float4 fv[4];
    float ssum = 0.f, ssq = 0.f;
#pragma unroll
    for (int i = 0; i < 4; ++i) {
      float4 xv = *(const float4*)(xr + 4 * lane + 256 * i);
      float4 d4 = *(const float4*)(dr + 4 * lane + 256 * i);
      fv[i].x = xv.x + scale * d4.x;
      fv[i].y = xv.y + scale * d4.y;
      fv[i].z = xv.z + scale * d4.z;
      fv[i].w = xv.w + scale * d4.w;
      ssum += fv[i].x + fv[i].y + fv[i].z + fv[i].w;
      ssq += fv[i].x * fv[i].x + fv[i].y * fv[i].y + fv[i].z * fv[i].z + fv[i].w * fv[i].w;
    }
#pragma unroll
    for (int m = 1; m < 64; m <<= 1) {
      ssum += __shfl_xor(ssum, m);
      ssq += __shfl_xor(ssq, m);
    }
    float mu = ssum * (1.0f / 1024.0f);
    float var = ssq * (1.0f / 1024.0f) - mu * mu;
    float inv = rsqrtf(var + 1e-5f);
    float* orow = out + (size_t)(m0 + row) * DM;
#pragma unroll
    for (int i = 0; i < 4; ++i) {
      float4 o;
      o.x = (fv[i].x - mu) * inv * g4[i].x + be4[i].x;
      o.y = (fv[i].y - mu) * inv * g4[i].y + be4[i].y;
      o.z = (fv[i].z - mu) * inv * g4[i].z + be4[i].z;
      o.w = (fv[i].w - mu) * inv * g4[i].w + be4[i].w;
      *(float4*)(orow + 4 * lane + 256 * i) = o;
    }
  }
}

extern "C" void kernel_launch(void* const* d_in, const int* in_sizes, int n_in,
                              void* d_out, int out_size, void* d_ws, size_t ws_size,
                              hipStream_t stream) {
  const float* x      = (const float*)d_in[0];
  const float* sigraw = (const float*)d_in[1];
  const float* knots  = (const float*)d_in[2];
  const float* temp   = (const float*)d_in[3];
  const float* cw1    = (const float*)d_in[4];
  const float* cb1    = (const float*)d_in[5];
  const float* cw2    = (const float*)d_in[6];
  const float* cb2    = (const float*)d_in[7];
  const float* sw1    = (const float*)d_in[8];
  const float* sb1    = (const float*)d_in[9];
  const float* sw2    = (const float*)d_in[10];
  const float* sb2    = (const float*)d_in[11];
  const float* dirs   = (const float*)d_in[12];
  const float* gma    = (const float*)d_in[13];
  const float* bta    = (const float*)d_in[14];
  const float* oscale = (const float*)d_in[15];
  float* out = (float*)d_out;

  unsigned short* wsB = (unsigned short*)d_ws;   // 32*24*1024*2 = 1,572,864 B... (ushort count 786,432)

  hipLaunchKernelGGL(prep_kernel, dim3(32), dim3(256), 0, stream,
                     sigraw, cw1, wsB);
  hipLaunchKernelGGL(fused_kernel, dim3(N_TOK / 64), dim3(512), 0, stream,
                     x, wsB, cb1, cw2, cb2, knots, temp,
                     sw1, sb1, sw2, sb2, dirs, gma, bta, oscale, out);
}